// Round 2
// baseline (340.996 us; speedup 1.0000x reference)
//
#include <hip/hip_runtime.h>
#include <stdint.h>

// Problem constants
#define BT    (256*2048)      // 524288 tokens
#define DIN   25
#define DP    128
#define WTOK  32              // tokens per wave (2 row-tiles of 16)
#define NBLK  (BT/(4*WTOK))   // 4096 blocks of 4 waves
#define HS    132             // h row stride (bf16 elems): ds_write_b16 2-way, ds_read_b128 ~2-way (free)

typedef __attribute__((ext_vector_type(8))) __bf16          bf16x8;
typedef __attribute__((ext_vector_type(8))) unsigned short  u16x8;
typedef __attribute__((ext_vector_type(4))) float           f32x4;

// Per-wave private LDS slot (NO cross-wave sharing -> zero __syncthreads):
//   [0, 8448)      x-stage (3200 B) UNION h (32*132*2 = 8448 B; x dead before h written)
//   [8448, 10496)  xn A-frags: 2 tiles * 1024 B
#define WSLOT 10496
#define SMB   (4*WSLOT)       // 41984 B -> 3 blocks/CU (LDS-bound), 12 waves/CU

// ws layout (bytes): [w1' frags 8192][w2 frags 32768][b1' f32 512]
#define WS_W2  8192
#define WS_B1  40960

__device__ __forceinline__ unsigned short f2bf(float f) {
  unsigned int u = __float_as_uint(f);
  u += 0x7fffu + ((u >> 16) & 1u);          // round-to-nearest-even
  return (unsigned short)(u >> 16);
}

// exact-erf GELU via A&S 7.1.26 (|eps|<=1.5e-7)
__device__ __forceinline__ float gelu_exact(float x) {
  float z  = 0.70710678118654752f * x;
  float az = __builtin_fabsf(z);
  float t  = __builtin_amdgcn_rcpf(1.0f + 0.3275911f * az);
  float p  = t*(0.254829592f + t*(-0.284496736f + t*(1.421413741f +
             t*(-1.453152027f + t*1.061405429f))));
  float e  = __expf(-z*z);
  float erf_az = 1.0f - p*e;
  float erf_z  = (x < 0.f) ? -erf_az : erf_az;
  return 0.5f * x * (1.0f + erf_z);
}

__device__ __forceinline__ void async16(void* lds, const void* g) {
  __builtin_amdgcn_global_load_lds(
      (const __attribute__((address_space(1))) unsigned int*)g,
      (__attribute__((address_space(3)))       unsigned int*)lds, 16, 0, 0);
}

// ---------------------------------------------------------------------------
// Prep: fold LN affine into weights, pack to bf16 MFMA B-frag lane order.
//   w1'[k][n] = gamma[k] * w1[k][n]          (K padded 25->32 with zeros)
//   b1'[n]    = b1[n] + sum_k beta[k]*w1[k][n]
// B-frag (16x16x32): elem(lane,j) = B[k=(lane>>4)*8+j][n = nt*16 + (lane&15)]
// ---------------------------------------------------------------------------
__global__ void prep_kernel(const float* __restrict__ w1, const float* __restrict__ w2,
                            const float* __restrict__ gam, const float* __restrict__ bet,
                            const float* __restrict__ b1,
                            unsigned short* __restrict__ wf) {
  int idx = blockIdx.x * 256 + threadIdx.x;
  if (idx < 40 * 512) {
    int f = idx >> 9, r = idx & 511, l = r >> 3, j = r & 7;
    float val;
    if (f < 8) {                       // w1' frag, nt = f
      int k = (l >> 4) * 8 + j;
      int n = f * 16 + (l & 15);
      val = (k < DIN) ? gam[k] * w1[k * DP + n] : 0.f;
    } else {                           // w2 frag
      int g = f - 8, nt = g >> 2, ks = g & 3;
      int k = ks * 32 + (l >> 4) * 8 + j;
      int n = nt * 16 + (l & 15);
      val = w2[k * DP + n];
    }
    wf[idx] = f2bf(val);
  } else if (idx < 40 * 512 + DP) {    // b1'
    int n = idx - 40 * 512;
    float s = b1[n];
    for (int k = 0; k < DIN; k++) s += bet[k] * w1[k * DP + n];
    ((float*)((char*)wf + WS_B1))[n] = s;
  }
}

// ---------------------------------------------------------------------------
// Fused LN -> mm1(+b1',GELU) -> mm2(+b2). BARRIER-FREE: each wave owns 32
// tokens end-to-end in a private LDS slot; waves never synchronize.
// ---------------------------------------------------------------------------
__global__ __launch_bounds__(256, 3) void fused_kernel(
    const float* __restrict__ x, const float* __restrict__ b2,
    const unsigned short* __restrict__ wfr, float* __restrict__ out) {
  __shared__ __align__(16) unsigned char smem[SMB];
  const int tid  = threadIdx.x;
  const int lane = tid & 63, w = tid >> 6;
  const int quad = lane >> 4, l15 = lane & 15;
  unsigned char* base = smem + w * WSLOT;
  const long long t0 = ((long long)blockIdx.x * 4 + w) * WTOK;
  const unsigned char* wfb = (const unsigned char*)wfr;
  const float* b1p = (const float*)(wfb + WS_B1);

  // ---- stage this wave's x slice (32 tok * 25 f32 = 3200 B = 200 x 16B) ----
  {
    const float* src = x + t0 * DIN;
    for (int c = lane; c < 200; c += 64)                 // 3 full + 1 partial issue
      async16(base + c * 16, src + c * 4);
  }
  // preload biases while the DMA flies (VMEM to VGPR, independent)
  float b1v[8], b2v[8];
#pragma unroll
  for (int nt = 0; nt < 8; nt++) { b1v[nt] = b1p[nt*16 + l15]; b2v[nt] = b2[nt*16 + l15]; }
  bf16x8 wb1[8];
#pragma unroll
  for (int nt = 0; nt < 8; nt++)
    wb1[nt] = *(const bf16x8*)(wfb + nt * 1024 + lane * 16);

  asm volatile("s_waitcnt vmcnt(0)" ::: "memory");       // x slice resident in LDS

  // ---- LayerNorm: token tt = lane&31 (both halves redundant), pack xn A-frags ----
  {
    const int tt = lane & 31, half = lane >> 5;
    const float* xr = (const float*)(base + tt * (DIN * 4));
    float xv[DIN];
    float s = 0.f;
#pragma unroll
    for (int j = 0; j < DIN; j++) { xv[j] = xr[j]; s += xv[j]; }
    float mu = s * (1.f / DIN);
    float v = 0.f;
#pragma unroll
    for (int j = 0; j < DIN; j++) { float d = xv[j] - mu; v += d * d; }
    float inv = rsqrtf(v * (1.f / DIN) + 1e-5f);
    const int mt = tt >> 4, mr = tt & 15;
    unsigned char* fb = base + 8448 + mt * 1024;
#pragma unroll
    for (int qq = 0; qq < 2; qq++) {
      int q = 2 * half + qq;
      u16x8 pk;
#pragma unroll
      for (int j = 0; j < 8; j++) {
        int k = q * 8 + j;
        pk[j] = (k < DIN) ? f2bf((xv[k] - mu) * inv) : (unsigned short)0;
      }
      *(u16x8*)(fb + (mr + 16 * q) * 16) = pk;           // ds_write_b128, conflict-free
    }
  }

  // ---- mm1: h = gelu(xn @ w1' + b1') ; h -> LDS (bf16, row-major stride HS) ----
  const f32x4 zf = {0.f, 0.f, 0.f, 0.f};
  bf16x8 a0 = *(const bf16x8*)(base + 8448 + lane * 16);
  bf16x8 a1 = *(const bf16x8*)(base + 8448 + 1024 + lane * 16);
  unsigned short* hb = (unsigned short*)base;            // x region dead now
#pragma unroll
  for (int nt = 0; nt < 8; nt++) {
    f32x4 c0 = __builtin_amdgcn_mfma_f32_16x16x32_bf16(a0, wb1[nt], zf, 0, 0, 0);
    f32x4 c1 = __builtin_amdgcn_mfma_f32_16x16x32_bf16(a1, wb1[nt], zf, 0, 0, 0);
    int col = nt * 16 + l15;
#pragma unroll
    for (int r = 0; r < 4; r++) {
      int row = quad * 4 + r;
      hb[row * HS + col]        = f2bf(gelu_exact(c0[r] + b1v[nt]));
      hb[(16 + row) * HS + col] = f2bf(gelu_exact(c1[r] + b1v[nt]));
    }
  }

  // ---- mm2: out = h @ w2 + b2 ----
  bf16x8 aA[2][4];
#pragma unroll
  for (int mi = 0; mi < 2; mi++)
#pragma unroll
    for (int ks = 0; ks < 4; ks++)
      aA[mi][ks] = *(const bf16x8*)(base + (mi*16 + l15) * (HS*2) + ks*64 + quad*16);

#pragma unroll 2
  for (int nt = 0; nt < 8; nt++) {
    bf16x8 wf2[4];
#pragma unroll
    for (int ks = 0; ks < 4; ks++)
      wf2[ks] = *(const bf16x8*)(wfb + WS_W2 + ((nt*4 + ks) * 1024) + lane * 16);
    f32x4 c0 = zf, c1 = zf;
#pragma unroll
    for (int ks = 0; ks < 4; ks++) {
      c0 = __builtin_amdgcn_mfma_f32_16x16x32_bf16(aA[0][ks], wf2[ks], c0, 0, 0, 0);
      c1 = __builtin_amdgcn_mfma_f32_16x16x32_bf16(aA[1][ks], wf2[ks], c1, 0, 0, 0);
    }
    int col = nt * 16 + l15;
    float bias = b2v[nt];
#pragma unroll
    for (int r = 0; r < 4; r++) {
      int row = quad * 4 + r;
      out[(t0 + row) * DP + col]      = c0[r] + bias;
      out[(t0 + 16 + row) * DP + col] = c1[r] + bias;
    }
  }
}

extern "C" void kernel_launch(void* const* d_in, const int* in_sizes, int n_in,
                              void* d_out, int out_size, void* d_ws, size_t ws_size,
                              hipStream_t stream) {
  const float* x   = (const float*)d_in[0];
  const float* gam = (const float*)d_in[1];
  const float* bet = (const float*)d_in[2];
  const float* w1  = (const float*)d_in[3];
  const float* b1  = (const float*)d_in[4];
  const float* w2  = (const float*)d_in[5];
  const float* b2  = (const float*)d_in[6];
  float* out = (float*)d_out;
  unsigned short* wf = (unsigned short*)d_ws;   // 41.5 KB packed weights + b1'

  prep_kernel<<<81, 256, 0, stream>>>(w1, w2, gam, bet, b1, wf);
  fused_kernel<<<NBLK, 256, 0, stream>>>(x, b2, wf, out);
}